// Round 11
// baseline (674.357 us; speedup 1.0000x reference)
//
#include <hip/hip_runtime.h>
#include <hip/hip_fp16.h>

#define B_ 512
#define T_ 512
#define H_ 64
#define K_ 4

// ---- workspace layout (shared prefix, both paths) ----
//   wht  f16 [K*3][8][64][8]  @ 0        (98304 B)  chunk-transposed W_h
//   wit  f16 [3][8][64][8]    @ 98304    (24576 B)  chunk-transposed W_i
//   flag int                  @ 123136
// fallback path:
//   xh16 f16 [B*T*H]          @ 131072   (33554432 B)
// fast path:
//   xh16  f16 [B*T*H]         @ 131072    (33554432 B)
//   iproj f32 [B*T][3][64]    @ 33685504  (201326592 B)
//   hh    f16 [B*T][64]       @ 235012096 (33554432 B)
#define WS_WIT_OFF   98304
#define WS_FLAG_OFF  123136
#define WS_XH_OFF    131072
#define WS_IPJ_OFF   33685504ULL
#define WS_HH_OFF    235012096ULL
#define WS_NEED_FAST 268566528ULL

// fallback LDS (gru_seq6): Wh [0,98304) ; Wi [98304,122880) ; h scratch @122880
#define LDS_HSC_OFF  122880
#define LDS_TOTAL    123392
#define STAGE_U4     7680

// fast-path LDS (gru_seq15): r-gate image [K][8][64][8] f16 = 32768 B @0 ;
// h scratch @32768 ([buf:2][64] halves = 256 B)
#define LDS15_HSC_OFF 32768
#define LDS15_TOTAL   33024

typedef _Float16 half2_t __attribute__((ext_vector_type(2)));

union Q { uint4 u; half2_t h[4]; };  // 16 B = 4 packed half2

__device__ __forceinline__ float fdot2f(half2_t a, half2_t b, float c) {
#if __has_builtin(__builtin_amdgcn_fdot2)
    return __builtin_amdgcn_fdot2(a, b, c, false);
#else
    return fmaf((float)a[0], (float)b[0], fmaf((float)a[1], (float)b[1], c));
#endif
}

__device__ __forceinline__ half2_t pkh2(float a, float b) {
    return __builtin_bit_cast(half2_t, __builtin_amdgcn_cvt_pkrtz(a, b));
}

// Detect whether mask buffer is 1-byte bools or int32 0/1 (little-endian).
__global__ void detect_mask_kernel(const unsigned char* __restrict__ mb, int* __restrict__ flag) {
    __shared__ int cnt;
    if (threadIdx.x == 0) cnt = 0;
    __syncthreads();
    int c = 0;
    for (int i = threadIdx.x; i < 4096; i += blockDim.x)
        if ((i & 3) != 0 && mb[i] != 0) c++;
    atomicAdd(&cnt, c);
    __syncthreads();
    if (threadIdx.x == 0) *flag = (cnt > 0) ? 1 : 0;  // 1 => uint8 bools, 0 => int32
}

// Weights -> f16 chunk-transposed: dst u4 index (mat*8 + j/8)*64 + i
__global__ void convert_weights_kernel(const float* __restrict__ Whr, const float* __restrict__ Whz,
                                       const float* __restrict__ Whn, const float* __restrict__ Wir,
                                       const float* __restrict__ Wiz, const float* __restrict__ Win,
                                       __half* __restrict__ wht, __half* __restrict__ wit) {
    int idx = blockIdx.x * 256 + threadIdx.x;
    if (idx < K_ * 3 * H_ * H_) {
        int mat = idx >> 12;            // k*3+g
        int i   = (idx >> 6) & 63;
        int j   = idx & 63;
        int k   = mat / 3, g = mat - 3 * k;
        const float* src = (g == 0) ? Whr : (g == 1) ? Whz : Whn;
        wht[((mat * 8 + (j >> 3)) * 64 + i) * 8 + (j & 7)] = __float2half(src[(k * H_ + i) * H_ + j]);
    }
    if (idx < 3 * H_ * H_) {
        int g = idx >> 12;
        int i = (idx >> 6) & 63;
        int j = idx & 63;
        const float* src = (g == 0) ? Wir : (g == 1) ? Wiz : Win;
        wit[((g * 8 + (j >> 3)) * 64 + i) * 8 + (j & 7)] = __float2half(src[i * H_ + j]);
    }
}

// x f32 -> packed f16 (both paths)
__global__ void convert_x_kernel(const float* __restrict__ xf, __half* __restrict__ xh) {
    size_t i = (size_t)blockIdx.x * 256 + threadIdx.x;
    if (i >= (size_t)B_ * T_ * H_ / 8) return;
    const float4* p = (const float4*)xf + 2 * i;
    float4 a = p[0], b = p[1];
    Q o;
    o.h[0] = pkh2(a.x, a.y);
    o.h[1] = pkh2(a.z, a.w);
    o.h[2] = pkh2(b.x, b.y);
    o.h[3] = pkh2(b.z, b.w);
    ((uint4*)xh)[i] = o.u;
}

// ============================================================================
// FAST PATH: precompute input projections iproj[bt][3][64] f32 from xh16.
// v3: reads the f16-packed x (identical bits to the old inline conversion,
// same fdot2 accumulation order -> bit-identical results). Per-wave 8 rows
// with an alternating 2-buffer pipeline (load row r+2 while computing r+1);
// ~180 VGPR -> 2 waves/SIMD, 8 waves/CU; 8192 blocks. The old v2 was ~4x
// over roofline (220-VGPR occupancy cap + serial row pipeline).
// ============================================================================
__global__ __launch_bounds__(256, 1)
void iproj_kernel(const __half* __restrict__ xh16, const __half* __restrict__ wit,
                  const float* __restrict__ b_ir, const float* __restrict__ b_iz,
                  const float* __restrict__ b_in, float* __restrict__ iproj) {
    const int lane = threadIdx.x & 63;
    const int wv   = threadIdx.x >> 6;   // 0..3
    Q wr[8], wz[8], wn[8];
    const uint4* wp = (const uint4*)wit + lane;
#pragma unroll
    for (int q = 0; q < 8; q++) {
        wr[q].u = wp[q * 64];
        wz[q].u = wp[512 + q * 64];
        wn[q].u = wp[1024 + q * 64];
    }
    const float bir = b_ir[lane], biz = b_iz[lane], bin = b_in[lane];
    const int bt_base = blockIdx.x * 32 + wv * 8;

#define IPJ_LOAD(DST, ROW)                                                      \
    { const uint4* xp = (const uint4*)(xh16 + (size_t)(ROW) * H_);              \
      _Pragma("unroll") for (int q = 0; q < 8; q++) DST[q].u = xp[q]; }
#define IPJ_COMP(SRC, ROW)                                                      \
    { float sir = bir, siz = biz, sin_ = bin;                                   \
      _Pragma("unroll") for (int q = 0; q < 8; q++)                             \
        _Pragma("unroll") for (int p = 0; p < 4; p++) {                         \
            sir  = fdot2f(wr[q].h[p], SRC[q].h[p], sir);                        \
            siz  = fdot2f(wz[q].h[p], SRC[q].h[p], siz);                        \
            sin_ = fdot2f(wn[q].h[p], SRC[q].h[p], sin_);                       \
        }                                                                       \
      float* op = iproj + (size_t)(ROW) * 192;                                  \
      op[lane] = sir; op[64 + lane] = siz; op[128 + lane] = sin_; }

    Q x0[8], x1[8];
    IPJ_LOAD(x0, bt_base)
    IPJ_LOAD(x1, bt_base + 1)
#pragma unroll
    for (int rp = 0; rp < 8; rp += 2) {
        IPJ_COMP(x0, bt_base + rp)
        if (rp + 2 < 8) IPJ_LOAD(x0, bt_base + rp + 2)
        IPJ_COMP(x1, bt_base + rp + 1)
        if (rp + 3 < 8) IPJ_LOAD(x1, bt_base + rp + 3)
    }
#undef IPJ_LOAD
#undef IPJ_COMP
}

// ============================================================================
// FAST PATH sequential kernel gru_seq15 = seq14 with the mid-step r-gate
// lgkmcnt(0) stall DELETED. seq12 (all-LDS weights) and seq14 (L2+LDS mix)
// both measured ~1400 cyc/step despite totally different byte-splits ->
// serial-structure-bound, so remove serial waits:
//  - r-gate LDS prefetch for k(t+1) moves from step END to right after the
//    GLD issue. The END-of-step lgkmcnt(0) (required for the h roundtrip
//    anyway) then already covers it -> next step's r matvec needs NO wait
//    (it sits textually after that lgkm(0)+sched_barrier, so it cannot be
//    hoisted above -- rule-#18-safe), and r-reads get a full step in flight.
//  - vmem census unchanged: [16 GLD][hh store] per step -> vmcnt(1) normal,
//    vmcnt(27) post-chunk (26 distinct bulk loads, wrap-not-clamp keeps the
//    dead final chunk CSE-proof).
//  - DS census: [rpref x8][h-store][h-read x8] -> one lgkm(0) at step end.
// 512 blocks x 64 thr (1 wave = 1 chain), 33 KB LDS -> 2 blocks/CU.
// ============================================================================
#define DSR(DST, ADDR, OFF) \
    asm volatile("ds_read_b128 %0, %1 offset:" #OFF : "=v"(DST) : "v"(ADDR));
#define GLD(DST, PTR, OFF) \
    asm volatile("global_load_dwordx4 %0, %1, off offset:" #OFF : "=v"(DST) : "v"(PTR));

#define PREFL8(RN, VB)                                                          \
    DSR(RN[0].u, VB, 0)    DSR(RN[1].u, VB, 1024)                               \
    DSR(RN[2].u, VB, 2048) DSR(RN[3].u, VB, 3072)                               \
    DSR(RN[4].u, VB, 4096) DSR(RN[5].u, VB, 5120)                               \
    DSR(RN[6].u, VB, 6144) DSR(RN[7].u, VB, 7168)

#define BSEL(K, A0, A1, A2, A3) (((K) == 0) ? (A0) : ((K) == 1) ? (A1) : ((K) == 2) ? (A2) : (A3))

#define LOADCHUNK(IPR, IPZ, IPN, CTXV, MSKV, T0)                                \
{                                                                               \
    __builtin_amdgcn_sched_barrier(0);                                          \
    const int t0c = (T0);                                                       \
    _Pragma("unroll") for (int s = 0; s < 8; s++) {                             \
        /* wrap (not clamp): keeps 24 DISTINCT addresses in the dead final */   \
        /* chunk so no CSE -> the vmcnt(27) census stays exact.            */   \
        int tcl = t0c + s; tcl = (tcl < T_) ? tcl : s;                          \
        const float* ipp = iproj + (size_t)(bt0 + tcl) * 192;                   \
        IPR[s] = ipp[lane]; IPZ[s] = ipp[64 + lane]; IPN[s] = ipp[128 + lane];  \
    }                                                                           \
    int tcc = t0c + (lane & 7); tcc = (tcc < T_) ? tcc : (T_ - 1);              \
    CTXV = ctx[bt0 + tcc];                                                      \
    MSKV = (int)maskb[(size_t)(bt0 + tcc) << mshift];                           \
    __builtin_amdgcn_sched_barrier(0);                                          \
}

// NW: exact vmcnt census at step top. Normal step: prev step issued 16 GLD
// then 1 hh store -> vmcnt(1) leaves exactly the store (in-order retirement).
// Post-chunk step (SS==0): + 26 bulk loads after -> vmcnt(27).
#define STEP15(TT, SS, NW, ZC, NC, RC, ZN, NN, RN, KNU_EXPR, IPR, IPZ, IPN, CTXC, MSKC) \
{                                                                               \
    const int tt  = (TT);                                                       \
    const int kcu = __builtin_amdgcn_readlane(CTXC, SS);                        \
    const int knu = (KNU_EXPR);                                                 \
    /* [0] this step's z/n regs (GLD'd last step) are ready */                  \
    asm volatile("s_waitcnt vmcnt(" #NW ")" ::: "memory");                      \
    __builtin_amdgcn_sched_barrier(0);                                          \
    /* [1] issue z/n global prefetch for expert knu = k(t+1) (oldest vmem) */   \
    { const char* gb0 = whtl + (size_t)knu * 24576 + 8192;                      \
      const char* gb1 = gb0 + 4096;                                             \
      const char* gb2 = gb0 + 8192;                                             \
      const char* gb3 = gb0 + 12288;                                            \
      GLD(ZN[0].u, gb0, 0) GLD(ZN[1].u, gb0, 1024)                              \
      GLD(ZN[2].u, gb0, 2048) GLD(ZN[3].u, gb0, 3072)                           \
      GLD(ZN[4].u, gb1, 0) GLD(ZN[5].u, gb1, 1024)                              \
      GLD(ZN[6].u, gb1, 2048) GLD(ZN[7].u, gb1, 3072)                           \
      GLD(NN[0].u, gb2, 0) GLD(NN[1].u, gb2, 1024)                              \
      GLD(NN[2].u, gb2, 2048) GLD(NN[3].u, gb2, 3072)                           \
      GLD(NN[4].u, gb3, 0) GLD(NN[5].u, gb3, 1024)                              \
      GLD(NN[6].u, gb3, 2048) GLD(NN[7].u, gb3, 3072) }                         \
    /* [1.5] r-gate LDS prefetch for knu -- drains under THIS step's work,  */  \
    /* covered by this step's final lgkmcnt(0)                               */ \
    { const unsigned int vb = lds0 + (unsigned int)(knu * 8192) + ((unsigned int)lane << 4); \
      PREFL8(RN, vb) }                                                          \
    __builtin_amdgcn_sched_barrier(0);                                          \
    /* [2] z,n matvec on current regs (per-gate chains, order-preserving) */    \
    float shr, shz, shn;                                                        \
    { float a4[4] = {0,0,0,0};                                                  \
      _Pragma("unroll") for (int q = 0; q < 8; q++)                             \
        _Pragma("unroll") for (int p = 0; p < 4; p++)                           \
          a4[q >> 1] = fdot2f(ZC[q].h[p], hq[q].h[p], a4[q >> 1]);              \
      shz = (a4[0] + a4[1]) + (a4[2] + a4[3]); }                                \
    { float a4[4] = {0,0,0,0};                                                  \
      _Pragma("unroll") for (int q = 0; q < 8; q++)                             \
        _Pragma("unroll") for (int p = 0; p < 4; p++)                           \
          a4[q >> 1] = fdot2f(NC[q].h[p], hq[q].h[p], a4[q >> 1]);              \
      shn = (a4[0] + a4[1]) + (a4[2] + a4[3]); }                                \
    /* [3] r matvec -- NO wait: RC was drained by prev step's lgkmcnt(0) */     \
    { float a4[4] = {0,0,0,0};                                                  \
      _Pragma("unroll") for (int q = 0; q < 8; q++)                             \
        _Pragma("unroll") for (int p = 0; p < 4; p++)                           \
          a4[q >> 1] = fdot2f(RC[q].h[p], hq[q].h[p], a4[q >> 1]);              \
      shr = (a4[0] + a4[1]) + (a4[2] + a4[3]); }                                \
    /* [4] epilogue (identical math/order to verified kernels) */               \
    const float bhr = BSEL(kcu, bR0, bR1, bR2, bR3);                            \
    const float bhz = BSEL(kcu, bZ0, bZ1, bZ2, bZ3);                            \
    const float bhn = BSEL(kcu, bN0, bN1, bN2, bN3);                            \
    const float mcv = (__builtin_amdgcn_readlane(MSKC, SS) != 0) ? 1.0f : 0.0f; \
    const float arv = IPR[SS] + shr + bhr;                                      \
    const float azv = IPZ[SS] + shz + bhz;                                      \
    const float rr  = 1.0f / (1.0f + __expf(-arv));                             \
    const float zz  = 1.0f / (1.0f + __expf(-azv));                             \
    const float aa  = IPN[SS] + rr * (shn + bhn);                               \
    const float nn2 = 2.0f / (1.0f + __expf(-2.0f * aa)) - 1.0f;                \
    float hnew = nn2 + zz * (hreg - nn2);                                       \
    hnew = (mcv > 0.5f) ? hnew : hreg;                                          \
    hreg = hnew;                                                                \
    const __half h16 = __float2half(hnew);                                      \
    hh0[(size_t)tt * H_ + lane] = h16;     /* vmem store (younger than GLDs) */ \
    /* [5] h round trip (DS tail: rpref already queued ahead, long done) */     \
    hsc[((SS & 1) << 6) + lane] = h16;                                          \
    __builtin_amdgcn_wave_barrier();                                            \
    { const uint4* hp = (const uint4*)(hsc + ((SS & 1) << 6));                  \
      _Pragma("unroll") for (int q = 0; q < 8; q++) hq[q].u = hp[q]; }          \
    __builtin_amdgcn_wave_barrier();                                            \
    asm volatile("s_waitcnt lgkmcnt(0)" ::: "memory");                          \
    __builtin_amdgcn_sched_barrier(0);                                          \
}

#define RUNCHUNK15(T0, IPR, IPZ, IPN, CTXC, MSKC, CTXN)                         \
    STEP15(T0 + 0, 0, 27, zA, nA, rA, zB, nB, rB, __builtin_amdgcn_readlane(CTXC, 1), IPR, IPZ, IPN, CTXC, MSKC) \
    STEP15(T0 + 1, 1, 1,  zB, nB, rB, zA, nA, rA, __builtin_amdgcn_readlane(CTXC, 2), IPR, IPZ, IPN, CTXC, MSKC) \
    STEP15(T0 + 2, 2, 1,  zA, nA, rA, zB, nB, rB, __builtin_amdgcn_readlane(CTXC, 3), IPR, IPZ, IPN, CTXC, MSKC) \
    STEP15(T0 + 3, 3, 1,  zB, nB, rB, zA, nA, rA, __builtin_amdgcn_readlane(CTXC, 4), IPR, IPZ, IPN, CTXC, MSKC) \
    STEP15(T0 + 4, 4, 1,  zA, nA, rA, zB, nB, rB, __builtin_amdgcn_readlane(CTXC, 5), IPR, IPZ, IPN, CTXC, MSKC) \
    STEP15(T0 + 5, 5, 1,  zB, nB, rB, zA, nA, rA, __builtin_amdgcn_readlane(CTXC, 6), IPR, IPZ, IPN, CTXC, MSKC) \
    STEP15(T0 + 6, 6, 1,  zA, nA, rA, zB, nB, rB, __builtin_amdgcn_readlane(CTXC, 7), IPR, IPZ, IPN, CTXC, MSKC) \
    STEP15(T0 + 7, 7, 1,  zB, nB, rB, zA, nA, rA, __builtin_amdgcn_readlane(CTXN, 0), IPR, IPZ, IPN, CTXC, MSKC)

__global__ __launch_bounds__(64, 1)
void gru_seq15(const float* __restrict__ iproj, const int* __restrict__ ctx,
               const unsigned char* __restrict__ maskb, const int* __restrict__ flagp,
               const __half* __restrict__ wht,
               const float* __restrict__ b_hr, const float* __restrict__ b_hz,
               const float* __restrict__ b_hn, __half* __restrict__ hh) {
    extern __shared__ __align__(16) char smem[];
    uint4* swr = (uint4*)smem;           // r-gate image [K][512] u4 (32 KB)
    const int lane = threadIdx.x;        // 0..63, single wave
    const int bt0  = blockIdx.x * T_;

    // stage r-gate sub-image: expert k's r part = first 512 u4 of its block
    {
        const uint4* g = (const uint4*)wht;
#pragma unroll 4
        for (int i = lane; i < 2048; i += 64)
            swr[i] = g[(i >> 9) * 1536 + (i & 511)];
    }
    __syncthreads();

    const unsigned int lds0 = (unsigned int)(uintptr_t)smem;
    const char* whtl = (const char*)wht + ((size_t)lane << 4);

    const int flag   = *flagp;
    const int mshift = flag ? 0 : 2;
    __half* hh0 = hh + (size_t)bt0 * H_;
    __half* hsc = (__half*)(smem + LDS15_HSC_OFF);

    // expert biases -> registers (12 VGPRs)
    const float bR0 = b_hr[lane],       bR1 = b_hr[64 + lane];
    const float bR2 = b_hr[128 + lane], bR3 = b_hr[192 + lane];
    const float bZ0 = b_hz[lane],       bZ1 = b_hz[64 + lane];
    const float bZ2 = b_hz[128 + lane], bZ3 = b_hz[192 + lane];
    const float bN0 = b_hn[lane],       bN1 = b_hn[64 + lane];
    const float bN2 = b_hn[128 + lane], bN3 = b_hn[192 + lane];

    float hreg = 0.0f;
    Q hq[8];
#pragma unroll
    for (int q = 0; q < 8; q++) hq[q].u = make_uint4(0u, 0u, 0u, 0u);

    // double-buffered 8-step chunks of iproj/ctx/mask
    float ipAr[8], ipAz[8], ipAn[8];
    float ipBr[8], ipBz[8], ipBn[8];
    int ctxA, mskA, ctxB, mskB;
    LOADCHUNK(ipAr, ipAz, ipAn, ctxA, mskA, 0)

    // prologue: W[k0] into A buffers (compiler loads; auto-waited)
    Q zA[8], nA[8], rA[8], zB[8], nB[8], rB[8];
    {
        const int k0u = __builtin_amdgcn_readlane(ctxA, 0);
        const uint4* gwp = (const uint4*)wht + k0u * 1536 + lane;
#pragma unroll
        for (int q = 0; q < 8; q++) {
            zA[q].u = gwp[512 + q * 64];
            nA[q].u = gwp[1024 + q * 64];
            rA[q].u = swr[k0u * 512 + q * 64 + lane];
        }
    }

#pragma unroll 1
    for (int c = 0; c < 64; c += 2) {
        const int t0a = c << 3, t0b = t0a + 8;
        LOADCHUNK(ipBr, ipBz, ipBn, ctxB, mskB, t0b)
        RUNCHUNK15(t0a, ipAr, ipAz, ipAn, ctxA, mskA, ctxB)
        LOADCHUNK(ipAr, ipAz, ipAn, ctxA, mskA, t0b + 8)
        RUNCHUNK15(t0b, ipBr, ipBz, ipBn, ctxB, mskB, ctxA)
    }
}

// logits from stored f16 h history: out[bt][o] = sum_h hh[bt][h]*Wo_w[o][h] + Wo_b[o]
__global__ __launch_bounds__(256, 1)
void logits_kernel(const __half* __restrict__ hh, const float* __restrict__ Wo_w,
                   const float* __restrict__ Wo_b, float* __restrict__ out) {
    const int bt = blockIdx.x * 256 + threadIdx.x;
    const uint4* hp = (const uint4*)(hh + (size_t)bt * H_);
    const float wob0 = Wo_b[0], wob1 = Wo_b[1];
    float l0 = 0.0f, l1 = 0.0f;
#pragma unroll
    for (int q = 0; q < 8; q++) {
        Q h8; h8.u = hp[q];
#pragma unroll
        for (int p = 0; p < 4; p++) {
            const int j = q * 8 + p * 2;
            const float v0 = (float)h8.h[p][0];
            const float v1 = (float)h8.h[p][1];
            l0 = fmaf(v0, Wo_w[j], l0);
            l0 = fmaf(v1, Wo_w[j + 1], l0);
            l1 = fmaf(v0, Wo_w[64 + j], l1);
            l1 = fmaf(v1, Wo_w[64 + j + 1], l1);
        }
    }
    *(float2*)(out + (size_t)bt * 2) = make_float2(l0 + wob0, l1 + wob1);
}

// ============================================================================
// FALLBACK PATH (ws too small for iproj): verified gru_seq6, unchanged.
// ============================================================================
#define STEP(TT, WCUR, WNXT, BUF)                                              \
{                                                                              \
    const int tt = (TT);                                                       \
    const int tn = (tt + 1 < T_) ? tt + 1 : T_ - 1;                            \
    Q xq[8];                                                                   \
    { const uint4* xp = (const uint4*)(xh16 + (size_t)(bt0 + tt) * H_);        \
      _Pragma("unroll") for (int q = 0; q < 8; q++) xq[q].u = xp[q]; }         \
    float ar4[4] = {0,0,0,0}, az4[4] = {0,0,0,0}, an4[4] = {0,0,0,0};          \
    _Pragma("unroll") for (int q = 0; q < 8; q++) {                            \
        _Pragma("unroll") for (int p = 0; p < 4; p++) {                        \
            ar4[q >> 1] = fdot2f(WCUR[q].h[p],      hq[q].h[p], ar4[q >> 1]);  \
            az4[q >> 1] = fdot2f(WCUR[8 + q].h[p],  hq[q].h[p], az4[q >> 1]);  \
            an4[q >> 1] = fdot2f(WCUR[16 + q].h[p], hq[q].h[p], an4[q >> 1]);  \
        }                                                                      \
    }                                                                          \
    const float shr = (ar4[0] + ar4[1]) + (ar4[2] + ar4[3]);                   \
    const float shz = (az4[0] + az4[1]) + (az4[2] + az4[3]);                   \
    const float shn = (an4[0] + an4[1]) + (an4[2] + an4[3]);                   \
    float sir = bir, siz = biz, sin_ = bin;                                    \
    _Pragma("unroll") for (int q = 0; q < 8; q++) {                            \
        Q wr, wz, wn;                                                          \
        wr.u = swi[q * 64 + lane];                                             \
        wz.u = swi[512 + q * 64 + lane];                                       \
        wn.u = swi[1024 + q * 64 + lane];                                      \
        _Pragma("unroll") for (int p = 0; p < 4; p++) {                        \
            sir  = fdot2f(wr.h[p], xq[q].h[p], sir);                           \
            siz  = fdot2f(wz.h[p], xq[q].h[p], siz);                           \
            sin_ = fdot2f(wn.h[p], xq[q].h[p], sin_);                          \
        }                                                                      \
    }                                                                          \
    const int kn = __builtin_amdgcn_readfirstlane(ctx[bt0 + tn]);              \
    const unsigned char mn = maskb[(size_t)(bt0 + tn) << mshift];              \
    const float bhr_n = b_hr[kn * H_ + lane];                                  \
    const float bhz_n = b_hz[kn * H_ + lane];                                  \
    const float bhn_n = b_hn[kn * H_ + lane];                                  \
    { const uint4* wp = sw + kn * 1536 + lane;                                 \
      _Pragma("unroll") for (int q = 0; q < 8; q++) {                          \
        WNXT[q].u      = wp[q * 64];                                           \
        WNXT[8 + q].u  = wp[512 + q * 64];                                     \
        WNXT[16 + q].u = wp[1024 + q * 64];                                    \
      } }                                                                      \
    const float arv = sir + shr + bhr_c;                                       \
    const float azv = siz + shz + bhz_c;                                       \
    const float rr  = 1.0f / (1.0f + __expf(-arv));                            \
    const float zz  = 1.0f / (1.0f + __expf(-azv));                            \
    const float aa  = sin_ + rr * (shn + bhn_c);                               \
    const float nn2 = 2.0f / (1.0f + __expf(-2.0f * aa)) - 1.0f;               \
    float hnew = nn2 + zz * (hreg - nn2);                                      \
    hnew = (mc > 0.5f) ? hnew : hreg;                                          \
    hreg = hnew;                                                               \
    { __half* hb = hsc + ((BUF) << 6);                                         \
      hb[lane] = __float2half(hnew);                                           \
      __builtin_amdgcn_wave_barrier();                                         \
      const uint4* hp = (const uint4*)hb;                                      \
      _Pragma("unroll") for (int q = 0; q < 8; q++) hq[q].u = hp[q];           \
      __builtin_amdgcn_wave_barrier(); }                                       \
    { float l0 = hnew * wo0, l1 = hnew * wo1;                                  \
      _Pragma("unroll") for (int m = 32; m >= 1; m >>= 1) {                    \
          l0 += __shfl_xor(l0, m, 64);                                         \
          l1 += __shfl_xor(l1, m, 64);                                         \
      }                                                                        \
      if (lane == 0) *(float2*)(outp + tt * 2) = make_float2(l0 + wob0, l1 + wob1); } \
    bhr_c = bhr_n; bhz_c = bhz_n; bhn_c = bhn_n;                               \
    mc = mn ? 1.0f : 0.0f;                                                     \
}

__global__ __launch_bounds__(128, 1)
void gru_seq6(const __half* __restrict__ xh16, const int* __restrict__ ctx,
              const unsigned char* __restrict__ maskb, const int* __restrict__ flagp,
              const __half* __restrict__ wht,
              const float* __restrict__ b_ir, const float* __restrict__ b_iz,
              const float* __restrict__ b_in, const float* __restrict__ b_hr,
              const float* __restrict__ b_hz, const float* __restrict__ b_hn,
              const float* __restrict__ Wo_w, const float* __restrict__ Wo_b,
              float* __restrict__ out) {
    extern __shared__ __align__(16) char smem[];
    uint4* sw  = (uint4*)smem;          // Wh image (6144 u4)
    uint4* swi = sw + 6144;             // Wi image (1536 u4)

    const int tid  = threadIdx.x;
    const int lane = tid & 63;
    const int wv   = tid >> 6;          // 0,1
    const int b    = blockIdx.x * 2 + wv;

    {
        const uint4* gsrc = (const uint4*)wht;
#pragma unroll 1
        for (int i = tid; i < STAGE_U4; i += 128) sw[i] = gsrc[i];
    }
    __syncthreads();

    const int flag   = *flagp;
    const int mshift = flag ? 0 : 2;
    const int bt0    = b * T_;

    const float bir = b_ir[lane], biz = b_iz[lane], bin = b_in[lane];
    const float wo0 = Wo_w[lane], wo1 = Wo_w[64 + lane];
    const float wob0 = Wo_b[0], wob1 = Wo_b[1];

    __half* hsc = (__half*)(smem + LDS_HSC_OFF + (wv << 8));
    float*  outp = out + (size_t)b * T_ * 2;

    float hreg = 0.0f;
    Q hq[8];
#pragma unroll
    for (int q = 0; q < 8; q++) hq[q].u = make_uint4(0u, 0u, 0u, 0u);

    Q wA[24], wB[24];
    const int k0 = __builtin_amdgcn_readfirstlane(ctx[bt0]);
    float mc = maskb[(size_t)bt0 << mshift] ? 1.0f : 0.0f;
    float bhr_c = b_hr[k0 * H_ + lane];
    float bhz_c = b_hz[k0 * H_ + lane];
    float bhn_c = b_hn[k0 * H_ + lane];
    {
        const uint4* wp = sw + k0 * 1536 + lane;
#pragma unroll
        for (int q = 0; q < 8; q++) {
            wA[q].u      = wp[q * 64];
            wA[8 + q].u  = wp[512 + q * 64];
            wA[16 + q].u = wp[1024 + q * 64];
        }
    }

#pragma unroll 1
    for (int t = 0; t < T_; t += 2) {
        STEP(t,     wA, wB, 0)
        STEP(t + 1, wB, wA, 1)
    }
}

extern "C" void kernel_launch(void* const* d_in, const int* in_sizes, int n_in,
                              void* d_out, int out_size, void* d_ws, size_t ws_size,
                              hipStream_t stream) {
    const float* x    = (const float*)d_in[0];
    const int*   ctx  = (const int*)d_in[1];
    const void*  mask = d_in[2];
    const float* W_ir = (const float*)d_in[3];
    const float* W_iz = (const float*)d_in[4];
    const float* W_in = (const float*)d_in[5];
    const float* bir  = (const float*)d_in[6];
    const float* biz  = (const float*)d_in[7];
    const float* bin  = (const float*)d_in[8];
    const float* W_hr = (const float*)d_in[9];
    const float* W_hz = (const float*)d_in[10];
    const float* W_hn = (const float*)d_in[11];
    const float* bhr  = (const float*)d_in[12];
    const float* bhz  = (const float*)d_in[13];
    const float* bhn  = (const float*)d_in[14];
    const float* Wo_w = (const float*)d_in[15];
    const float* Wo_b = (const float*)d_in[16];

    char* ws = (char*)d_ws;
    __half* wht  = (__half*)ws;
    __half* wit  = (__half*)(ws + WS_WIT_OFF);
    int*    flag = (int*)(ws + WS_FLAG_OFF);
    __half* xh16 = (__half*)(ws + WS_XH_OFF);

    detect_mask_kernel<<<1, 256, 0, stream>>>((const unsigned char*)mask, flag);
    convert_weights_kernel<<<192, 256, 0, stream>>>(W_hr, W_hz, W_hn, W_ir, W_iz, W_in,
                                                    wht, wit);
    convert_x_kernel<<<8192, 256, 0, stream>>>(x, xh16);

    if (ws_size >= (size_t)WS_NEED_FAST) {
        // fast path: f16-input pipelined iproj + wait-trimmed dual-counter
        // weight streaming + deferred logits
        float*  iproj = (float*)(ws + WS_IPJ_OFF);
        __half* hh    = (__half*)(ws + WS_HH_OFF);
        iproj_kernel<<<B_ * T_ / 32, 256, 0, stream>>>(xh16, wit, bir, biz, bin, iproj);
        (void)hipFuncSetAttribute((const void*)gru_seq15,
                                  hipFuncAttributeMaxDynamicSharedMemorySize, LDS15_TOTAL);
        gru_seq15<<<B_, 64, LDS15_TOTAL, stream>>>(
            iproj, ctx, (const unsigned char*)mask, flag, wht, bhr, bhz, bhn, hh);
        logits_kernel<<<B_ * T_ / 256, 256, 0, stream>>>(hh, Wo_w, Wo_b, (float*)d_out);
    } else {
        // fallback: previous verified pipeline
        (void)hipFuncSetAttribute((const void*)gru_seq6,
                                  hipFuncAttributeMaxDynamicSharedMemorySize, LDS_TOTAL);
        gru_seq6<<<B_ / 2, 128, LDS_TOTAL, stream>>>(
            xh16, ctx, (const unsigned char*)mask, flag, wht,
            bir, biz, bin, bhr, bhz, bhn, Wo_w, Wo_b, (float*)d_out);
    }
}

// Round 13
// 520.331 us; speedup vs baseline: 1.2960x; 1.2960x over previous
//
#include <hip/hip_runtime.h>
#include <hip/hip_fp16.h>

#define B_ 512
#define T_ 512
#define H_ 64
#define K_ 4

// ---- workspace layout (shared prefix, both paths) ----
//   wht  f16 [K*3][8][64][8]  @ 0        (98304 B)  chunk-transposed W_h
//   wit  f16 [3][8][64][8]    @ 98304    (24576 B)  chunk-transposed W_i
//   flag int                  @ 123136
// fallback path:
//   xh16 f16 [B*T*H]          @ 131072   (33554432 B)
// fast path (hh ALIASES xh16 -- xh16 is dead once iproj_kernel completes,
// and hh is only written/read strictly after it on the same stream):
//   xh16/hh f16 [B*T*H]       @ 131072    (33554432 B)
//   iproj   f32 [B*T][3][64]  @ 33685504  (201326592 B)
// total need = 235012096 B (fits the 256 MiB harness workspace)
#define WS_WIT_OFF   98304
#define WS_FLAG_OFF  123136
#define WS_XH_OFF    131072
#define WS_HH_OFF    131072ULL
#define WS_IPJ_OFF   33685504ULL
#define WS_NEED_FAST 235012096ULL

// fallback LDS (gru_seq6): Wh [0,98304) ; Wi [98304,122880) ; h scratch @122880
#define LDS_HSC_OFF  122880
#define LDS_TOTAL    123392
#define STAGE_U4     7680

// fast-path LDS (gru_seq14): r-gate image [K][8][64][8] f16 = 32768 B @0 ;
// h scratch @32768 ([buf:2][64] halves = 256 B)
#define LDS14_HSC_OFF 32768
#define LDS14_TOTAL   33024

typedef _Float16 half2_t __attribute__((ext_vector_type(2)));

union Q { uint4 u; half2_t h[4]; };  // 16 B = 4 packed half2

__device__ __forceinline__ float fdot2f(half2_t a, half2_t b, float c) {
#if __has_builtin(__builtin_amdgcn_fdot2)
    return __builtin_amdgcn_fdot2(a, b, c, false);
#else
    return fmaf((float)a[0], (float)b[0], fmaf((float)a[1], (float)b[1], c));
#endif
}

__device__ __forceinline__ half2_t pkh2(float a, float b) {
    return __builtin_bit_cast(half2_t, __builtin_amdgcn_cvt_pkrtz(a, b));
}

// Detect whether mask buffer is 1-byte bools or int32 0/1 (little-endian).
__global__ void detect_mask_kernel(const unsigned char* __restrict__ mb, int* __restrict__ flag) {
    __shared__ int cnt;
    if (threadIdx.x == 0) cnt = 0;
    __syncthreads();
    int c = 0;
    for (int i = threadIdx.x; i < 4096; i += blockDim.x)
        if ((i & 3) != 0 && mb[i] != 0) c++;
    atomicAdd(&cnt, c);
    __syncthreads();
    if (threadIdx.x == 0) *flag = (cnt > 0) ? 1 : 0;  // 1 => uint8 bools, 0 => int32
}

// Weights -> f16 chunk-transposed: dst u4 index (mat*8 + j/8)*64 + i
__global__ void convert_weights_kernel(const float* __restrict__ Whr, const float* __restrict__ Whz,
                                       const float* __restrict__ Whn, const float* __restrict__ Wir,
                                       const float* __restrict__ Wiz, const float* __restrict__ Win,
                                       __half* __restrict__ wht, __half* __restrict__ wit) {
    int idx = blockIdx.x * 256 + threadIdx.x;
    if (idx < K_ * 3 * H_ * H_) {
        int mat = idx >> 12;            // k*3+g
        int i   = (idx >> 6) & 63;
        int j   = idx & 63;
        int k   = mat / 3, g = mat - 3 * k;
        const float* src = (g == 0) ? Whr : (g == 1) ? Whz : Whn;
        wht[((mat * 8 + (j >> 3)) * 64 + i) * 8 + (j & 7)] = __float2half(src[(k * H_ + i) * H_ + j]);
    }
    if (idx < 3 * H_ * H_) {
        int g = idx >> 12;
        int i = (idx >> 6) & 63;
        int j = idx & 63;
        const float* src = (g == 0) ? Wir : (g == 1) ? Wiz : Win;
        wit[((g * 8 + (j >> 3)) * 64 + i) * 8 + (j & 7)] = __float2half(src[i * H_ + j]);
    }
}

// x f32 -> packed f16 (both paths)
__global__ void convert_x_kernel(const float* __restrict__ xf, __half* __restrict__ xh) {
    size_t i = (size_t)blockIdx.x * 256 + threadIdx.x;
    if (i >= (size_t)B_ * T_ * H_ / 8) return;
    const float4* p = (const float4*)xf + 2 * i;
    float4 a = p[0], b = p[1];
    Q o;
    o.h[0] = pkh2(a.x, a.y);
    o.h[1] = pkh2(a.z, a.w);
    o.h[2] = pkh2(b.x, b.y);
    o.h[3] = pkh2(b.z, b.w);
    ((uint4*)xh)[i] = o.u;
}

// ============================================================================
// FAST PATH: precompute input projections iproj[bt][3][64] f32 from xh16.
// Reads the f16-packed x (identical bits to the old inline conversion, same
// fdot2 accumulation order -> bit-identical results). Per-wave 8 rows with an
// alternating 2-buffer pipeline; 8192 blocks.
// ============================================================================
__global__ __launch_bounds__(256, 1)
void iproj_kernel(const __half* __restrict__ xh16, const __half* __restrict__ wit,
                  const float* __restrict__ b_ir, const float* __restrict__ b_iz,
                  const float* __restrict__ b_in, float* __restrict__ iproj) {
    const int lane = threadIdx.x & 63;
    const int wv   = threadIdx.x >> 6;   // 0..3
    Q wr[8], wz[8], wn[8];
    const uint4* wp = (const uint4*)wit + lane;
#pragma unroll
    for (int q = 0; q < 8; q++) {
        wr[q].u = wp[q * 64];
        wz[q].u = wp[512 + q * 64];
        wn[q].u = wp[1024 + q * 64];
    }
    const float bir = b_ir[lane], biz = b_iz[lane], bin = b_in[lane];
    const int bt_base = blockIdx.x * 32 + wv * 8;

#define IPJ_LOAD(DST, ROW)                                                      \
    { const uint4* xp = (const uint4*)(xh16 + (size_t)(ROW) * H_);              \
      _Pragma("unroll") for (int q = 0; q < 8; q++) DST[q].u = xp[q]; }
#define IPJ_COMP(SRC, ROW)                                                      \
    { float sir = bir, siz = biz, sin_ = bin;                                   \
      _Pragma("unroll") for (int q = 0; q < 8; q++)                             \
        _Pragma("unroll") for (int p = 0; p < 4; p++) {                         \
            sir  = fdot2f(wr[q].h[p], SRC[q].h[p], sir);                        \
            siz  = fdot2f(wz[q].h[p], SRC[q].h[p], siz);                        \
            sin_ = fdot2f(wn[q].h[p], SRC[q].h[p], sin_);                       \
        }                                                                       \
      float* op = iproj + (size_t)(ROW) * 192;                                  \
      op[lane] = sir; op[64 + lane] = siz; op[128 + lane] = sin_; }

    Q x0[8], x1[8];
    IPJ_LOAD(x0, bt_base)
    IPJ_LOAD(x1, bt_base + 1)
#pragma unroll
    for (int rp = 0; rp < 8; rp += 2) {
        IPJ_COMP(x0, bt_base + rp)
        if (rp + 2 < 8) IPJ_LOAD(x0, bt_base + rp + 2)
        IPJ_COMP(x1, bt_base + rp + 1)
        if (rp + 3 < 8) IPJ_LOAD(x1, bt_base + rp + 3)
    }
#undef IPJ_LOAD
#undef IPJ_COMP
}

// ============================================================================
// FAST PATH sequential kernel gru_seq14 — EXACT round-10 verified code
// (passed, absmax 0.0078125, 303 us). seq15's deleted mid-step lgkmcnt was
// round 12's only sync-structure change and is the prime suspect for the
// correctness failure; reverted. Dual-counter weight streaming with exact
// counted vmcnt + bulk chunking:
//  - z/n gates (16 reads) via asm global_load_dwordx4 from L2-hot wht
//    (vmcnt path); r gate (8 reads) via asm ds_read from a 32 KB LDS image,
//    issued after the end-of-step lgkmcnt(0).
//  - vmem census: [16 GLD][hh store] per step -> vmcnt(1) normal, vmcnt(27)
//    post-chunk (26 distinct bulk loads; wrap-not-clamp keeps the dead final
//    chunk CSE-proof).
// 512 blocks x 64 thr (1 wave = 1 chain), 33 KB LDS -> 2 blocks/CU.
// ============================================================================
#define DSR(DST, ADDR, OFF) \
    asm volatile("ds_read_b128 %0, %1 offset:" #OFF : "=v"(DST) : "v"(ADDR));
#define GLD(DST, PTR, OFF) \
    asm volatile("global_load_dwordx4 %0, %1, off offset:" #OFF : "=v"(DST) : "v"(PTR));

#define PREFL8(RN, VB)                                                          \
    DSR(RN[0].u, VB, 0)    DSR(RN[1].u, VB, 1024)                               \
    DSR(RN[2].u, VB, 2048) DSR(RN[3].u, VB, 3072)                               \
    DSR(RN[4].u, VB, 4096) DSR(RN[5].u, VB, 5120)                               \
    DSR(RN[6].u, VB, 6144) DSR(RN[7].u, VB, 7168)

#define BSEL(K, A0, A1, A2, A3) (((K) == 0) ? (A0) : ((K) == 1) ? (A1) : ((K) == 2) ? (A2) : (A3))

#define LOADCHUNK(IPR, IPZ, IPN, CTXV, MSKV, T0)                                \
{                                                                               \
    __builtin_amdgcn_sched_barrier(0);                                          \
    const int t0c = (T0);                                                       \
    _Pragma("unroll") for (int s = 0; s < 8; s++) {                             \
        /* wrap (not clamp): keeps 24 DISTINCT addresses in the dead final */   \
        /* chunk so no CSE -> the vmcnt(27) census stays exact.            */   \
        int tcl = t0c + s; tcl = (tcl < T_) ? tcl : s;                          \
        const float* ipp = iproj + (size_t)(bt0 + tcl) * 192;                   \
        IPR[s] = ipp[lane]; IPZ[s] = ipp[64 + lane]; IPN[s] = ipp[128 + lane];  \
    }                                                                           \
    int tcc = t0c + (lane & 7); tcc = (tcc < T_) ? tcc : (T_ - 1);              \
    CTXV = ctx[bt0 + tcc];                                                      \
    MSKV = (int)maskb[(size_t)(bt0 + tcc) << mshift];                           \
    __builtin_amdgcn_sched_barrier(0);                                          \
}

// NW: exact vmcnt census at step top. Normal step: prev step issued 16 GLD
// then 1 hh store -> wait vmcnt(1) leaves exactly the store (in-order
// retirement). Post-chunk step (SS==0): + 26 bulk loads issued after ->
// vmcnt(27) leaves store+bulk flying.
#define STEP14(TT, SS, NW, ZC, NC, RC, ZN, NN, RN, KNU_EXPR, IPR, IPZ, IPN, CTXC, MSKC) \
{                                                                               \
    const int tt  = (TT);                                                       \
    const int kcu = __builtin_amdgcn_readlane(CTXC, SS);                        \
    const int knu = (KNU_EXPR);                                                 \
    /* [0] this step's z/n regs (GLD'd last step) are ready */                  \
    asm volatile("s_waitcnt vmcnt(" #NW ")" ::: "memory");                      \
    __builtin_amdgcn_sched_barrier(0);                                          \
    /* [1] issue z/n global prefetch for expert knu = k(t+1) (oldest vmem) */   \
    { const char* gb0 = whtl + (size_t)knu * 24576 + 8192;                      \
      const char* gb1 = gb0 + 4096;                                             \
      const char* gb2 = gb0 + 8192;                                             \
      const char* gb3 = gb0 + 12288;                                            \
      GLD(ZN[0].u, gb0, 0) GLD(ZN[1].u, gb0, 1024)                              \
      GLD(ZN[2].u, gb0, 2048) GLD(ZN[3].u, gb0, 3072)                           \
      GLD(ZN[4].u, gb1, 0) GLD(ZN[5].u, gb1, 1024)                              \
      GLD(ZN[6].u, gb1, 2048) GLD(ZN[7].u, gb1, 3072)                           \
      GLD(NN[0].u, gb2, 0) GLD(NN[1].u, gb2, 1024)                              \
      GLD(NN[2].u, gb2, 2048) GLD(NN[3].u, gb2, 3072)                           \
      GLD(NN[4].u, gb3, 0) GLD(NN[5].u, gb3, 1024)                              \
      GLD(NN[6].u, gb3, 2048) GLD(NN[7].u, gb3, 3072) }                         \
    __builtin_amdgcn_sched_barrier(0);                                          \
    /* [2] z,n matvec on current regs (per-gate chains, order-preserving) */    \
    float shr, shz, shn;                                                        \
    { float a4[4] = {0,0,0,0};                                                  \
      _Pragma("unroll") for (int q = 0; q < 8; q++)                             \
        _Pragma("unroll") for (int p = 0; p < 4; p++)                           \
          a4[q >> 1] = fdot2f(ZC[q].h[p], hq[q].h[p], a4[q >> 1]);              \
      shz = (a4[0] + a4[1]) + (a4[2] + a4[3]); }                                \
    { float a4[4] = {0,0,0,0};                                                  \
      _Pragma("unroll") for (int q = 0; q < 8; q++)                             \
        _Pragma("unroll") for (int p = 0; p < 4; p++)                           \
          a4[q >> 1] = fdot2f(NC[q].h[p], hq[q].h[p], a4[q >> 1]);              \
      shn = (a4[0] + a4[1]) + (a4[2] + a4[3]); }                                \
    /* [3] r matvec (r ds_reads from prev step end drained under z/n) */        \
    asm volatile("s_waitcnt lgkmcnt(0)" ::: "memory");                          \
    __builtin_amdgcn_sched_barrier(0);                                          \
    { float a4[4] = {0,0,0,0};                                                  \
      _Pragma("unroll") for (int q = 0; q < 8; q++)                             \
        _Pragma("unroll") for (int p = 0; p < 4; p++)                           \
          a4[q >> 1] = fdot2f(RC[q].h[p], hq[q].h[p], a4[q >> 1]);              \
      shr = (a4[0] + a4[1]) + (a4[2] + a4[3]); }                                \
    /* [4] epilogue (identical math/order to verified kernels) */               \
    const float bhr = BSEL(kcu, bR0, bR1, bR2, bR3);                            \
    const float bhz = BSEL(kcu, bZ0, bZ1, bZ2, bZ3);                            \
    const float bhn = BSEL(kcu, bN0, bN1, bN2, bN3);                            \
    const float mcv = (__builtin_amdgcn_readlane(MSKC, SS) != 0) ? 1.0f : 0.0f; \
    const float arv = IPR[SS] + shr + bhr;                                      \
    const float azv = IPZ[SS] + shz + bhz;                                      \
    const float rr  = 1.0f / (1.0f + __expf(-arv));                             \
    const float zz  = 1.0f / (1.0f + __expf(-azv));                             \
    const float aa  = IPN[SS] + rr * (shn + bhn);                               \
    const float nn2 = 2.0f / (1.0f + __expf(-2.0f * aa)) - 1.0f;                \
    float hnew = nn2 + zz * (hreg - nn2);                                       \
    hnew = (mcv > 0.5f) ? hnew : hreg;                                          \
    hreg = hnew;                                                                \
    const __half h16 = __float2half(hnew);                                      \
    hh0[(size_t)tt * H_ + lane] = h16;     /* store (younger than GLDs) */      \
    /* [5] h round trip (short DS tail: store + 8 reads only) */                \
    hsc[((SS & 1) << 6) + lane] = h16;                                          \
    __builtin_amdgcn_wave_barrier();                                            \
    { const uint4* hp = (const uint4*)(hsc + ((SS & 1) << 6));                  \
      _Pragma("unroll") for (int q = 0; q < 8; q++) hq[q].u = hp[q]; }          \
    __builtin_amdgcn_wave_barrier();                                            \
    asm volatile("s_waitcnt lgkmcnt(0)" ::: "memory");                          \
    __builtin_amdgcn_sched_barrier(0);                                          \
    /* [6] r-gate LDS prefetch for knu — drains under next z/n matvec */        \
    { const unsigned int vb = lds0 + (unsigned int)(knu * 8192) + ((unsigned int)lane << 4); \
      PREFL8(RN, vb) }                                                          \
    __builtin_amdgcn_sched_barrier(0);                                          \
}

#define RUNCHUNK14(T0, IPR, IPZ, IPN, CTXC, MSKC, CTXN)                         \
    STEP14(T0 + 0, 0, 27, zA, nA, rA, zB, nB, rB, __builtin_amdgcn_readlane(CTXC, 1), IPR, IPZ, IPN, CTXC, MSKC) \
    STEP14(T0 + 1, 1, 1,  zB, nB, rB, zA, nA, rA, __builtin_amdgcn_readlane(CTXC, 2), IPR, IPZ, IPN, CTXC, MSKC) \
    STEP14(T0 + 2, 2, 1,  zA, nA, rA, zB, nB, rB, __builtin_amdgcn_readlane(CTXC, 3), IPR, IPZ, IPN, CTXC, MSKC) \
    STEP14(T0 + 3, 3, 1,  zB, nB, rB, zA, nA, rA, __builtin_amdgcn_readlane(CTXC, 4), IPR, IPZ, IPN, CTXC, MSKC) \
    STEP14(T0 + 4, 4, 1,  zA, nA, rA, zB, nB, rB, __builtin_amdgcn_readlane(CTXC, 5), IPR, IPZ, IPN, CTXC, MSKC) \
    STEP14(T0 + 5, 5, 1,  zB, nB, rB, zA, nA, rA, __builtin_amdgcn_readlane(CTXC, 6), IPR, IPZ, IPN, CTXC, MSKC) \
    STEP14(T0 + 6, 6, 1,  zA, nA, rA, zB, nB, rB, __builtin_amdgcn_readlane(CTXC, 7), IPR, IPZ, IPN, CTXC, MSKC) \
    STEP14(T0 + 7, 7, 1,  zB, nB, rB, zA, nA, rA, __builtin_amdgcn_readlane(CTXN, 0), IPR, IPZ, IPN, CTXC, MSKC)

__global__ __launch_bounds__(64, 1)
void gru_seq14(const float* __restrict__ iproj, const int* __restrict__ ctx,
               const unsigned char* __restrict__ maskb, const int* __restrict__ flagp,
               const __half* __restrict__ wht,
               const float* __restrict__ b_hr, const float* __restrict__ b_hz,
               const float* __restrict__ b_hn, __half* __restrict__ hh) {
    extern __shared__ __align__(16) char smem[];
    uint4* swr = (uint4*)smem;           // r-gate image [K][512] u4 (32 KB)
    const int lane = threadIdx.x;        // 0..63, single wave
    const int bt0  = blockIdx.x * T_;

    // stage r-gate sub-image: expert k's r part = first 512 u4 of its block
    {
        const uint4* g = (const uint4*)wht;
#pragma unroll 4
        for (int i = lane; i < 2048; i += 64)
            swr[i] = g[(i >> 9) * 1536 + (i & 511)];
    }
    __syncthreads();

    const unsigned int lds0 = (unsigned int)(uintptr_t)smem;
    const char* whtl = (const char*)wht + ((size_t)lane << 4);

    const int flag   = *flagp;
    const int mshift = flag ? 0 : 2;
    __half* hh0 = hh + (size_t)bt0 * H_;
    __half* hsc = (__half*)(smem + LDS14_HSC_OFF);

    // expert biases -> registers (12 VGPRs)
    const float bR0 = b_hr[lane],       bR1 = b_hr[64 + lane];
    const float bR2 = b_hr[128 + lane], bR3 = b_hr[192 + lane];
    const float bZ0 = b_hz[lane],       bZ1 = b_hz[64 + lane];
    const float bZ2 = b_hz[128 + lane], bZ3 = b_hz[192 + lane];
    const float bN0 = b_hn[lane],       bN1 = b_hn[64 + lane];
    const float bN2 = b_hn[128 + lane], bN3 = b_hn[192 + lane];

    float hreg = 0.0f;
    Q hq[8];
#pragma unroll
    for (int q = 0; q < 8; q++) hq[q].u = make_uint4(0u, 0u, 0u, 0u);

    // double-buffered 8-step chunks of iproj/ctx/mask
    float ipAr[8], ipAz[8], ipAn[8];
    float ipBr[8], ipBz[8], ipBn[8];
    int ctxA, mskA, ctxB, mskB;
    LOADCHUNK(ipAr, ipAz, ipAn, ctxA, mskA, 0)

    // prologue: W[k0] into A buffers (compiler loads; auto-waited)
    Q zA[8], nA[8], rA[8], zB[8], nB[8], rB[8];
    {
        const int k0u = __builtin_amdgcn_readlane(ctxA, 0);
        const uint4* gwp = (const uint4*)wht + k0u * 1536 + lane;
#pragma unroll
        for (int q = 0; q < 8; q++) {
            zA[q].u = gwp[512 + q * 64];
            nA[q].u = gwp[1024 + q * 64];
            rA[q].u = swr[k0u * 512 + q * 64 + lane];
        }
    }

#pragma unroll 1
    for (int c = 0; c < 64; c += 2) {
        const int t0a = c << 3, t0b = t0a + 8;
        LOADCHUNK(ipBr, ipBz, ipBn, ctxB, mskB, t0b)
        RUNCHUNK14(t0a, ipAr, ipAz, ipAn, ctxA, mskA, ctxB)
        LOADCHUNK(ipAr, ipAz, ipAn, ctxA, mskA, t0b + 8)
        RUNCHUNK14(t0b, ipBr, ipBz, ipBn, ctxB, mskB, ctxA)
    }
}

// logits from stored f16 h history: out[bt][o] = sum_h hh[bt][h]*Wo_w[o][h] + Wo_b[o]
__global__ __launch_bounds__(256, 1)
void logits_kernel(const __half* __restrict__ hh, const float* __restrict__ Wo_w,
                   const float* __restrict__ Wo_b, float* __restrict__ out) {
    const int bt = blockIdx.x * 256 + threadIdx.x;
    const uint4* hp = (const uint4*)(hh + (size_t)bt * H_);
    const float wob0 = Wo_b[0], wob1 = Wo_b[1];
    float l0 = 0.0f, l1 = 0.0f;
#pragma unroll
    for (int q = 0; q < 8; q++) {
        Q h8; h8.u = hp[q];
#pragma unroll
        for (int p = 0; p < 4; p++) {
            const int j = q * 8 + p * 2;
            const float v0 = (float)h8.h[p][0];
            const float v1 = (float)h8.h[p][1];
            l0 = fmaf(v0, Wo_w[j], l0);
            l0 = fmaf(v1, Wo_w[j + 1], l0);
            l1 = fmaf(v0, Wo_w[64 + j], l1);
            l1 = fmaf(v1, Wo_w[64 + j + 1], l1);
        }
    }
    *(float2*)(out + (size_t)bt * 2) = make_float2(l0 + wob0, l1 + wob1);
}

// ============================================================================
// FALLBACK PATH (ws too small for iproj): verified gru_seq6, unchanged.
// ============================================================================
#define STEP(TT, WCUR, WNXT, BUF)                                              \
{                                                                              \
    const int tt = (TT);                                                       \
    const int tn = (tt + 1 < T_) ? tt + 1 : T_ - 1;                            \
    Q xq[8];                                                                   \
    { const uint4* xp = (const uint4*)(xh16 + (size_t)(bt0 + tt) * H_);        \
      _Pragma("unroll") for (int q = 0; q < 8; q++) xq[q].u = xp[q]; }         \
    float ar4[4] = {0,0,0,0}, az4[4] = {0,0,0,0}, an4[4] = {0,0,0,0};          \
    _Pragma("unroll") for (int q = 0; q < 8; q++) {                            \
        _Pragma("unroll") for (int p = 0; p < 4; p++) {                        \
            ar4[q >> 1] = fdot2f(WCUR[q].h[p],      hq[q].h[p], ar4[q >> 1]);  \
            az4[q >> 1] = fdot2f(WCUR[8 + q].h[p],  hq[q].h[p], az4[q >> 1]);  \
            an4[q >> 1] = fdot2f(WCUR[16 + q].h[p], hq[q].h[p], an4[q >> 1]);  \
        }                                                                      \
    }                                                                          \
    const float shr = (ar4[0] + ar4[1]) + (ar4[2] + ar4[3]);                   \
    const float shz = (az4[0] + az4[1]) + (az4[2] + az4[3]);                   \
    const float shn = (an4[0] + an4[1]) + (an4[2] + an4[3]);                   \
    float sir = bir, siz = biz, sin_ = bin;                                    \
    _Pragma("unroll") for (int q = 0; q < 8; q++) {                            \
        Q wr, wz, wn;                                                          \
        wr.u = swi[q * 64 + lane];                                             \
        wz.u = swi[512 + q * 64 + lane];                                       \
        wn.u = swi[1024 + q * 64 + lane];                                      \
        _Pragma("unroll") for (int p = 0; p < 4; p++) {                        \
            sir  = fdot2f(wr.h[p], xq[q].h[p], sir);                           \
            siz  = fdot2f(wz.h[p], xq[q].h[p], siz);                           \
            sin_ = fdot2f(wn.h[p], xq[q].h[p], sin_);                          \
        }                                                                      \
    }                                                                          \
    const int kn = __builtin_amdgcn_readfirstlane(ctx[bt0 + tn]);              \
    const unsigned char mn = maskb[(size_t)(bt0 + tn) << mshift];              \
    const float bhr_n = b_hr[kn * H_ + lane];                                  \
    const float bhz_n = b_hz[kn * H_ + lane];                                  \
    const float bhn_n = b_hn[kn * H_ + lane];                                  \
    { const uint4* wp = sw + kn * 1536 + lane;                                 \
      _Pragma("unroll") for (int q = 0; q < 8; q++) {                          \
        WNXT[q].u      = wp[q * 64];                                           \
        WNXT[8 + q].u  = wp[512 + q * 64];                                     \
        WNXT[16 + q].u = wp[1024 + q * 64];                                    \
      } }                                                                      \
    const float arv = sir + shr + bhr_c;                                       \
    const float azv = siz + shz + bhz_c;                                       \
    const float rr  = 1.0f / (1.0f + __expf(-arv));                            \
    const float zz  = 1.0f / (1.0f + __expf(-azv));                            \
    const float aa  = sin_ + rr * (shn + bhn_c);                               \
    const float nn2 = 2.0f / (1.0f + __expf(-2.0f * aa)) - 1.0f;               \
    float hnew = nn2 + zz * (hreg - nn2);                                      \
    hnew = (mc > 0.5f) ? hnew : hreg;                                          \
    hreg = hnew;                                                               \
    { __half* hb = hsc + ((BUF) << 6);                                         \
      hb[lane] = __float2half(hnew);                                           \
      __builtin_amdgcn_wave_barrier();                                         \
      const uint4* hp = (const uint4*)hb;                                      \
      _Pragma("unroll") for (int q = 0; q < 8; q++) hq[q].u = hp[q];           \
      __builtin_amdgcn_wave_barrier(); }                                       \
    { float l0 = hnew * wo0, l1 = hnew * wo1;                                  \
      _Pragma("unroll") for (int m = 32; m >= 1; m >>= 1) {                    \
          l0 += __shfl_xor(l0, m, 64);                                         \
          l1 += __shfl_xor(l1, m, 64);                                         \
      }                                                                        \
      if (lane == 0) *(float2*)(outp + tt * 2) = make_float2(l0 + wob0, l1 + wob1); } \
    bhr_c = bhr_n; bhz_c = bhz_n; bhn_c = bhn_n;                               \
    mc = mn ? 1.0f : 0.0f;                                                     \
}

__global__ __launch_bounds__(128, 1)
void gru_seq6(const __half* __restrict__ xh16, const int* __restrict__ ctx,
              const unsigned char* __restrict__ maskb, const int* __restrict__ flagp,
              const __half* __restrict__ wht,
              const float* __restrict__ b_ir, const float* __restrict__ b_iz,
              const float* __restrict__ b_in, const float* __restrict__ b_hr,
              const float* __restrict__ b_hz, const float* __restrict__ b_hn,
              const float* __restrict__ Wo_w, const float* __restrict__ Wo_b,
              float* __restrict__ out) {
    extern __shared__ __align__(16) char smem[];
    uint4* sw  = (uint4*)smem;          // Wh image (6144 u4)
    uint4* swi = sw + 6144;             // Wi image (1536 u4)

    const int tid  = threadIdx.x;
    const int lane = tid & 63;
    const int wv   = tid >> 6;          // 0,1
    const int b    = blockIdx.x * 2 + wv;

    {
        const uint4* gsrc = (const uint4*)wht;
#pragma unroll 1
    for (int i = tid; i < STAGE_U4; i += 128) sw[i] = gsrc[i];
    }
    __syncthreads();

    const int flag   = *flagp;
    const int mshift = flag ? 0 : 2;
    const int bt0    = b * T_;

    const float bir = b_ir[lane], biz = b_iz[lane], bin = b_in[lane];
    const float wo0 = Wo_w[lane], wo1 = Wo_w[64 + lane];
    const float wob0 = Wo_b[0], wob1 = Wo_b[1];

    __half* hsc = (__half*)(smem + LDS_HSC_OFF + (wv << 8));
    float*  outp = out + (size_t)b * T_ * 2;

    float hreg = 0.0f;
    Q hq[8];
#pragma unroll
    for (int q = 0; q < 8; q++) hq[q].u = make_uint4(0u, 0u, 0u, 0u);

    Q wA[24], wB[24];
    const int k0 = __builtin_amdgcn_readfirstlane(ctx[bt0]);
    float mc = maskb[(size_t)bt0 << mshift] ? 1.0f : 0.0f;
    float bhr_c = b_hr[k0 * H_ + lane];
    float bhz_c = b_hz[k0 * H_ + lane];
    float bhn_c = b_hn[k0 * H_ + lane];
    {
        const uint4* wp = sw + k0 * 1536 + lane;
#pragma unroll
        for (int q = 0; q < 8; q++) {
            wA[q].u      = wp[q * 64];
            wA[8 + q].u  = wp[512 + q * 64];
            wA[16 + q].u = wp[1024 + q * 64];
        }
    }

#pragma unroll 1
    for (int t = 0; t < T_; t += 2) {
        STEP(t,     wA, wB, 0)
        STEP(t + 1, wB, wA, 1)
    }
}

extern "C" void kernel_launch(void* const* d_in, const int* in_sizes, int n_in,
                              void* d_out, int out_size, void* d_ws, size_t ws_size,
                              hipStream_t stream) {
    const float* x    = (const float*)d_in[0];
    const int*   ctx  = (const int*)d_in[1];
    const void*  mask = d_in[2];
    const float* W_ir = (const float*)d_in[3];
    const float* W_iz = (const float*)d_in[4];
    const float* W_in = (const float*)d_in[5];
    const float* bir  = (const float*)d_in[6];
    const float* biz  = (const float*)d_in[7];
    const float* bin  = (const float*)d_in[8];
    const float* W_hr = (const float*)d_in[9];
    const float* W_hz = (const float*)d_in[10];
    const float* W_hn = (const float*)d_in[11];
    const float* bhr  = (const float*)d_in[12];
    const float* bhz  = (const float*)d_in[13];
    const float* bhn  = (const float*)d_in[14];
    const float* Wo_w = (const float*)d_in[15];
    const float* Wo_b = (const float*)d_in[16];

    char* ws = (char*)d_ws;
    __half* wht  = (__half*)ws;
    __half* wit  = (__half*)(ws + WS_WIT_OFF);
    int*    flag = (int*)(ws + WS_FLAG_OFF);
    __half* xh16 = (__half*)(ws + WS_XH_OFF);

    detect_mask_kernel<<<1, 256, 0, stream>>>((const unsigned char*)mask, flag);
    convert_weights_kernel<<<192, 256, 0, stream>>>(W_hr, W_hz, W_hn, W_ir, W_iz, W_in,
                                                    wht, wit);
    convert_x_kernel<<<8192, 256, 0, stream>>>(x, xh16);

    if (ws_size >= (size_t)WS_NEED_FAST) {
        // fast path: f16-input pipelined iproj + verified seq14 + deferred
        // logits. hh aliases xh16 (dead after iproj_kernel; strictly ordered
        // on one stream).
        float*  iproj = (float*)(ws + WS_IPJ_OFF);
        __half* hh    = (__half*)(ws + WS_HH_OFF);
        iproj_kernel<<<B_ * T_ / 32, 256, 0, stream>>>(xh16, wit, bir, biz, bin, iproj);
        (void)hipFuncSetAttribute((const void*)gru_seq14,
                                  hipFuncAttributeMaxDynamicSharedMemorySize, LDS14_TOTAL);
        gru_seq14<<<B_, 64, LDS14_TOTAL, stream>>>(
            iproj, ctx, (const unsigned char*)mask, flag, wht, bhr, bhz, bhn, hh);
        logits_kernel<<<B_ * T_ / 256, 256, 0, stream>>>(hh, Wo_w, Wo_b, (float*)d_out);
    } else {
        // fallback: previous verified pipeline
        (void)hipFuncSetAttribute((const void*)gru_seq6,
                                  hipFuncAttributeMaxDynamicSharedMemorySize, LDS_TOTAL);
        gru_seq6<<<B_ / 2, 128, LDS_TOTAL, stream>>>(
            xh16, ctx, (const unsigned char*)mask, flag, wht,
            bir, biz, bin, bhr, bhz, bhn, Wo_w, Wo_b, (float*)d_out);
    }
}